// Round 12
// baseline (2178.221 us; speedup 1.0000x reference)
//
#include <hip/hip_runtime.h>
#include <stdint.h>
#include <stddef.h>

typedef _Float16 f16;
typedef _Float16 f16x8 __attribute__((ext_vector_type(8)));
typedef float    f32x4 __attribute__((ext_vector_type(4)));

#define NB    16384   // batch
#define TT    100     // encoder steps
#define II    6       // input features
#define HH    128     // hidden
#define OLEN  20      // decoder steps
#define OO    2       // output features
#define RR    64      // batch rows per block

// f16-element offsets into workspace (8 recurrent mats are [512][128] = 65536 f16)
#define OFF_WHH0   0
#define OFF_WIH1   65536
#define OFF_WHH1   131072
#define OFF_DWIH0  196608
#define OFF_DWHH0  262144
#define OFF_DWIH1  327680
#define OFF_DWHH1  393216
#define OFF_WIH0P  458752          // [512][8] zero-padded (K=6 -> 8), prescaled
#define OFF_FCW    462848          // [2][128], NOT prescaled
#define OFF_BIAS_B 926208          // byte offset: 4*512 f32 combined prescaled biases
#define WS_BYTES   934400

#define SWZ(r) (((r) & 15) << 3)   // f16-unit XOR swizzle for h tiles

__device__ __forceinline__ float exp2_(float x) {
#if __has_builtin(__builtin_amdgcn_exp2f)
    return __builtin_amdgcn_exp2f(x);
#else
    return exp2f(x);
#endif
}
__device__ __forceinline__ float rcp_(float x) {
#if __has_builtin(__builtin_amdgcn_rcpf)
    return __builtin_amdgcn_rcpf(x);
#else
    return 1.f / x;
#endif
}

// ---------------- weight prep: fp32 -> f16, gate-prescaled; fuse+prescale biases ----
// gate rows (i,f,o) scaled by -log2(e) so sigmoid(z) = rcp(1+exp2(u));
// gate rows (g)     scaled by 2*log2(e) so tanh(z) = 1 - 2*rcp(1+exp2(u)).
__global__ __launch_bounds__(256) void prep_kernel(
    const float* eWih0, const float* eWhh0, const float* eWih1, const float* eWhh1,
    const float* dWih0, const float* dWhh0, const float* dWih1, const float* dWhh1,
    const float* ebi0,  const float* ebh0,  const float* ebi1,  const float* ebh1,
    const float* dbi0,  const float* dbh0,  const float* dbi1,  const float* dbh1,
    const float* fcW,   f16* w16, float* bws)
{
    const float GS0 = -1.4426950408889634f;   // i, f, o
    const float GS2 =  2.8853900817779268f;   // g
    int i0 = blockIdx.x * blockDim.x + threadIdx.x;
    int stride = gridDim.x * blockDim.x;
    const float* srcs[7] = {eWhh0, eWih1, eWhh1, dWih0, dWhh0, dWih1, dWhh1};
    for (int i = i0; i < 7 * 65536; i += stride) {
        int rem = i & 65535;
        float s = ((rem >> 14) == 2) ? GS2 : GS0;
        w16[i] = (f16)(srcs[i >> 16][rem] * s);
    }
    for (int i = i0; i < 512 * 8; i += stride) {
        int n = i >> 3, k = i & 7;
        float s = ((n >> 7) == 2) ? GS2 : GS0;
        w16[OFF_WIH0P + i] = (k < II) ? (f16)(eWih0[n * II + k] * s) : (f16)0.f;
    }
    for (int i = i0; i < OO * HH; i += stride) w16[OFF_FCW + i] = (f16)fcW[i];
    const float* bia[4] = {ebi0, ebi1, dbi0, dbi1};
    const float* bib[4] = {ebh0, ebh1, dbh0, dbh1};
    for (int i = i0; i < 4 * 512; i += stride) {
        int j = i & 511;
        float s = ((j >> 7) == 2) ? GS2 : GS0;
        bws[i] = (bia[i >> 9][j] + bib[i >> 9][j]) * s;
    }
}

// ---------------- main persistent LSTM kernel: 1 block = 64 batch rows ----------------
// R16 1606us; R23 half-bank + fc-fold: 1548us (verified twice).
// Envelope (R17-R26): latency-bound at 2 waves/SIMD; hard cap ~128 arch +
// 64 acc (resident banks / dual acc / 4-wave configs all spill).
// R28: FUSED act0 + phase-B state pass, m-granular acc handoff. The only
// act0 <-> phase-B dependency is per-acc-slot: zaccB(m) WARs act0's reads of
// acc[*][m]. Restructure the WHH1 (state-term) GEMM m-major and fuse per m:
//   { act0_m (trans, reads acc[*][m]) ; rebias_m ; 16 MFMAs for m }
// -> m+1's trans is independent of m's MFMAs; scheduler overlaps trans and
// MFMA pipes inside one fence region with ZERO extra registers (peak
// liveness = full WHH1 bank + acc = R23's existing peak). WIH1-L burst now
// issues at the fused tail (m=3,kk=1, when bankL dies) -- ~250cy exposed vs
// covered in R23; act0-hiding (~1-2.5Kcy) dominates. Decoder unchanged
// (acts there end their phase, no overlap partner).
__global__ __launch_bounds__(512, 2) void lstm_kernel(
    const float* __restrict__ xg, const f16* __restrict__ wsf,
    const float* __restrict__ bws, const float* __restrict__ fcb,
    float* __restrict__ out)
{
    __shared__ __align__(16) f16 h0s[2][RR][HH];     // 32KB, XOR-swizzled
    __shared__ __align__(16) f16 h1s[2][RR][HH];     // 32KB
    __shared__ __align__(16) f16 xs[2][RR][8];       // 2KB
    __shared__ __align__(16) f16 fcws[OO * HH];      // .5KB
    __shared__ float bias_s[4 * 512];                // 8KB
    __shared__ f32x4 c0s[4][512];                    // 32KB cell-0 state (per-thread slots)
    __shared__ f32x4 c1s[4][512];                    // 32KB cell-1 state -> 138.5KB

    const int tid = threadIdx.x;
    const int w   = tid >> 6;      // wave 0..7 -> hidden cols 16w..16w+15
    const int ln  = tid & 63;
    const int l15 = ln & 15;
    const int lg  = ln >> 4;       // lane k-group
    const int r0  = blockIdx.x * RR;

    // ---- init LDS (note: BOTH h1 buffers zeroed -- region 1 reads h1s[1] as h1(-1))
    for (int i = tid; i < OO * HH; i += 512) fcws[i] = wsf[OFF_FCW + i];
    for (int i = tid; i < 4 * 512; i += 512) bias_s[i] = bws[i];
    for (int i = tid; i < RR * HH; i += 512) {
        h0s[0][0][i] = (f16)0.f;
        h1s[0][0][i] = (f16)0.f;
        h1s[1][0][i] = (f16)0.f;
    }
    {
        const f32x4 z4 = {0.f, 0.f, 0.f, 0.f};
        for (int i = tid; i < 4 * 512; i += 512) {
            (&c0s[0][0])[i] = z4;
            (&c1s[0][0])[i] = z4;
        }
    }
    {   // stage x[t=0]
        int r = tid >> 3, k = tid & 7;
        float v = (k < II) ? xg[((size_t)(r0 + r) * TT + 0) * II + k] : 0.f;
        xs[0][r][k] = (f16)v;
    }

    f32x4 acc[4][4];    // [gate][m] accumulators (64 regs, MFMA C/D)
    f16x8 bankL[4][2];  // [gate][kk=0,1] streamed half-bank (32 regs)
    f16x8 bankH[4][2];  // [gate][kk=2,3] streamed half-bank (32 regs)
    f16x8 bX[4];        // encoder x-weights (16 regs; zero in lanes lg>0)

    {
        const f16x8 z = {};
        #pragma unroll
        for (int g = 0; g < 4; ++g) {
            const int nt = (g << 3) + w;
            bX[g] = (lg == 0)
                ? *(const f16x8*)(wsf + OFF_WIH0P + (size_t)((nt << 4) + l15) * 8)
                : z;
        }
    }

    // stream half of one matrix's B-fragments (kk-major). Offset tied through
    // an empty asm so loads re-execute per call (no hoisting into a
    // persistent spill-prone set -- the R5-R11 failure mode).
    auto loadHalfL = [&](unsigned offElems) {
        unsigned off = offElems;
        asm volatile("" : "+v"(off));
        const f16* W = wsf + off;
        #pragma unroll
        for (int kk = 0; kk < 2; ++kk)
            #pragma unroll
            for (int g = 0; g < 4; ++g) {
                const int nt = (g << 3) + w;
                bankL[g][kk] = *(const f16x8*)(W + (size_t)((nt << 4) + l15) * HH + (kk << 5) + (lg << 3));
            }
    };
    auto loadHalfH = [&](unsigned offElems) {
        unsigned off = offElems;
        asm volatile("" : "+v"(off));
        const f16* W = wsf + off;
        #pragma unroll
        for (int kk = 2; kk < 4; ++kk)
            #pragma unroll
            for (int g = 0; g < 4; ++g) {
                const int nt = (g << 3) + w;
                bankH[g][kk - 2] = *(const f16x8*)(W + (size_t)((nt << 4) + l15) * HH + (kk << 5) + (lg << 3));
            }
    };
    // fence + load: sched_barrier stops the new half-burst's loads from
    // hoisting above the previous consumer of that half (liveness doubling).
    #define LBL(off) do { __builtin_amdgcn_sched_barrier(0); loadHalfL(off); } while (0)
    #define LBH(off) do { __builtin_amdgcn_sched_barrier(0); loadHalfH(off); } while (0)

    auto zacc = [&](int cell) {
        #pragma unroll
        for (int g = 0; g < 4; ++g) {
            float b = bias_s[(cell << 9) | (g << 7) | (w << 4) | l15];
            f32x4 b4 = {b, b, b, b};
            #pragma unroll
            for (int m = 0; m < 4; ++m) acc[g][m] = b4;
        }
    };

    // K=64 half-GEMMs over ALL m-tiles with one half-bank (kk-major)
    auto kRL = [&](const f16* hsrc) {
        #pragma unroll
        for (int kk = 0; kk < 2; ++kk)
            #pragma unroll
            for (int m = 0; m < 4; ++m) {
                int r = (m << 4) + l15;
                int c = ((kk << 5) | (lg << 3)) ^ SWZ(r);
                f16x8 a = *(const f16x8*)(hsrc + (size_t)r * HH + c);
                #pragma unroll
                for (int g = 0; g < 4; ++g)
                    acc[g][m] = __builtin_amdgcn_mfma_f32_16x16x32_f16(a, bankL[g][kk], acc[g][m], 0, 0, 0);
            }
    };
    auto kRH = [&](const f16* hsrc) {
        #pragma unroll
        for (int kk = 2; kk < 4; ++kk)
            #pragma unroll
            for (int m = 0; m < 4; ++m) {
                int r = (m << 4) + l15;
                int c = ((kk << 5) | (lg << 3)) ^ SWZ(r);
                f16x8 a = *(const f16x8*)(hsrc + (size_t)r * HH + c);
                #pragma unroll
                for (int g = 0; g < 4; ++g)
                    acc[g][m] = __builtin_amdgcn_mfma_f32_16x16x32_f16(a, bankH[g][kk - 2], acc[g][m], 0, 0, 0);
            }
    };

    // encoder x-term: zero-padded K=32 MFMA (real K=6 in lanes lg==0); no bank dep
    auto mfx = [&](const f16 (*xsrc)[8]) {
        const f16x8 z = {};
        #pragma unroll
        for (int m = 0; m < 4; ++m) {
            int r = (m << 4) + l15;
            f16x8 a = lg ? z : *(const f16x8*)(&xsrc[r][0]);
            #pragma unroll
            for (int g = 0; g < 4; ++g)
                acc[g][m] = __builtin_amdgcn_mfma_f32_16x16x32_f16(a, bX[g], acc[g][m], 0, 0, 0);
        }
    };

    // gate nonlinearities; c in per-thread LDS slots; h -> hdst (parity-[p^1]
    // buffer, never read in the same region -> race-free).
    auto act = [&](f32x4 (*cs)[512], f16* hdst) {
        const int col = (w << 4) + l15;
        #pragma unroll
        for (int m = 0; m < 4; ++m) {
            f32x4 cold = cs[m][tid];
            f32x4 cnew;
            #pragma unroll
            for (int q = 0; q < 4; ++q) {
                float si = rcp_(1.f + exp2_(acc[0][m][q]));
                float sf = rcp_(1.f + exp2_(acc[1][m][q]));
                float tg = 1.f - 2.f * rcp_(1.f + exp2_(acc[2][m][q]));
                float so = rcp_(1.f + exp2_(acc[3][m][q]));
                float cn = sf * cold[q] + si * tg;
                cnew[q] = cn;
                float hn = so * (1.f - 2.f * rcp_(1.f + exp2_(2.8853900817779268f * cn)));
                int r = (m << 4) + (lg << 2) + q;
                hdst[(size_t)r * HH + (col ^ SWZ(r))] = (f16)hn;
            }
            cs[m][tid] = cnew;
        }
    };

    // FUSED: act0 (reads acc[*][m]) + phase-B state-term GEMM (rebias +
    // 16 MFMAs per m, full WHH1 bank). Per-m acc handoff: m+1's trans ops
    // are independent of m's MFMAs -> scheduler overlaps trans/MFMA pipes.
    // At m=3 kk=1 bankL's last use passes -> WIH1-L burst issues there.
    auto fusedB = [&](f32x4 (*cs)[512], f16* hdst, int cell, const f16* hsrc) {
        const int col = (w << 4) + l15;
        #pragma unroll
        for (int m = 0; m < 4; ++m) {
            // ---- act for this m ----
            f32x4 cold = cs[m][tid];
            f32x4 cnew;
            #pragma unroll
            for (int q = 0; q < 4; ++q) {
                float si = rcp_(1.f + exp2_(acc[0][m][q]));
                float sf = rcp_(1.f + exp2_(acc[1][m][q]));
                float tg = 1.f - 2.f * rcp_(1.f + exp2_(acc[2][m][q]));
                float so = rcp_(1.f + exp2_(acc[3][m][q]));
                float cn = sf * cold[q] + si * tg;
                cnew[q] = cn;
                float hn = so * (1.f - 2.f * rcp_(1.f + exp2_(2.8853900817779268f * cn)));
                int r = (m << 4) + (lg << 2) + q;
                hdst[(size_t)r * HH + (col ^ SWZ(r))] = (f16)hn;
            }
            cs[m][tid] = cnew;
            // ---- rebias + state-term GEMM for this m ----
            #pragma unroll
            for (int g = 0; g < 4; ++g) {
                float b = bias_s[(cell << 9) | (g << 7) | (w << 4) | l15];
                f32x4 b4 = {b, b, b, b};
                acc[g][m] = b4;
            }
            int r = (m << 4) + l15;
            #pragma unroll
            for (int kk = 0; kk < 4; ++kk) {
                int c = ((kk << 5) | (lg << 3)) ^ SWZ(r);
                f16x8 a = *(const f16x8*)(hsrc + (size_t)r * HH + c);
                #pragma unroll
                for (int g = 0; g < 4; ++g) {
                    f16x8 bk = (kk < 2) ? bankL[g][kk] : bankH[g][kk - 2];
                    acc[g][m] = __builtin_amdgcn_mfma_f32_16x16x32_f16(a, bk, acc[g][m], 0, 0, 0);
                }
                if (m == 3 && kk == 1) {   // bankL (WHH1-L) dead: stream WIH1-L
                    __builtin_amdgcn_sched_barrier(0);
                    loadHalfL(OFF_WIH1);
                }
            }
        }
    };

    LBL(OFF_WHH0);       // prologue: region 0's phase-A L-half
    __syncthreads();     // init visible

    // ============ encoder: 100 pipelined regions + tail, 1 barrier each ============
    // region t: phaseA(t):  gates0 = b0 + x(t)*Wih0 + h0s[p]*Whh0 -> h0s[p^1], c0
    //           phaseB(t-1):gates1 = b1 + h1s[p]*Whh1 + h0s[p]*Wih1 -> h1s[p^1], c1
    // (h0(t-1) lives in h0s[p]; h1(t-2) in h1s[p] -- all reads pre-region.)
    for (int t = 0; t < TT; ++t) {
        const int p = t & 1;
        float xv = 0.f;
        if (t + 1 < TT && (tid & 7) < II)
            xv = xg[((size_t)(r0 + (tid >> 3)) * TT + (t + 1)) * II + (tid & 7)];
        // phase A (WHH0-L preloaded at end of previous region)
        LBH(OFF_WHH0);                   // H-burst streams under zacc+mfx+kRL
        zacc(0);
        mfx(xs[p]);
        kRL(&h0s[p][0][0]);              // WHH0-L
        LBL(OFF_WHH1);                   // covered by kRH
        kRH(&h0s[p][0][0]);              // WHH0-H
        LBH(OFF_WHH1);                   // in flight into the fused loop
        if (t > 0) {
            // act0 fused with WHH1 state pass (h1(t-2)); loads WIH1-L at tail
            fusedB(c0s, &h0s[p ^ 1][0][0], 1, &h1s[p][0][0]);
            LBH(OFF_WIH1);               // covered by kRL(h0) below
            kRL(&h0s[p][0][0]);          // WIH1-L (input term h0(t-1), OLD buffer)
            LBL(OFF_WHH0);               // next region's A preload, under kRH+act1
            kRH(&h0s[p][0][0]);          // WIH1-H
            act(c1s, &h1s[p ^ 1][0][0]); // h1(t-1)
        } else {
            LBL(OFF_WHH0);               // region 1's A preload
            act(c0s, &h0s[p ^ 1][0][0]);
        }
        if (t + 1 < TT) xs[p ^ 1][tid >> 3][tid & 7] = (f16)xv;
        __builtin_amdgcn_sched_barrier(0);
        __syncthreads();                 // ONE barrier per region
    }
    // tail region: phaseB(99). After loop: h0(99)=h0s[0], h1(98)=h1s[0].
    {
        LBL(OFF_WHH1);
        LBH(OFF_WHH1);
        zacc(1);
        kRL(&h1s[0][0][0]);              // h1(98)
        LBL(OFF_WIH1);
        kRH(&h1s[0][0][0]);
        LBH(OFF_WIH1);
        kRL(&h0s[0][0][0]);              // h0(99)
        LBL(OFF_DWHH0);                  // decoder phase-A preload, under kRH+act1
        kRH(&h0s[0][0][0]);
        act(c1s, &h1s[1][0][0]);         // h1(99) -> h1s[1]
        __builtin_amdgcn_sched_barrier(0);
        __syncthreads();
    }
    // decoder entry: h0 cur = h0s[0], h1 cur = h1s[1]

    float fb = (tid < RR * OO) ? fcb[tid & 1] : 0.f;

    // fc: pred[r][o] = h1d(s) . fc_W[o] + fc_b[o]  (threads 0..127 only)
    auto fcOut = [&](int s, int qq) {
        if (tid < RR * OO) {
            int r = tid >> 1, o = tid & 1;
            float a = fb;
            const f16* hrow = &h1s[qq][r][0];
            #pragma unroll
            for (int ccol = 0; ccol < HH; ccol += 8) {
                int csw = ccol ^ SWZ(r);
                f16x8 hv = *(const f16x8*)(hrow + csw);
                f16x8 wv = *(const f16x8*)(&fcws[o * HH + ccol]);
                #pragma unroll
                for (int j = 0; j < 8; ++j) a += (float)hv[j] * (float)wv[j];
            }
            out[((size_t)(r0 + r) * OLEN + s) * OO + o] = a;
        }
    };

    // ============ decoder: 20 steps, 2 barriers/step ============
    // step s (q=s&1): reads h0s[q], h1s[q^1]; writes h0s[q^1] (A), h1s[q] (B).
    // Strictly serial (B(s) needs A(s)'s h0 through the barrier). fc(s-1) is
    // folded into A(s): it reads h1s[q^1], which A(s) only reads; h1s[q^1] is
    // next written at B(s+1), two barriers later -> race-free.
    for (int s = 0; s < OLEN; ++s) {
        const int q = s & 1;
        // Phase A: gates2 = b2 + h0d(s-1)*DWhh0 + h1d(s-1)*DWih0 -> h0d(s)
        LBH(OFF_DWHH0);                  // streams under zacc+fc+kRL
        zacc(2);
        if (s > 0) fcOut(s - 1, q ^ 1);  // waves 0-1 do fc; waves 2-7 proceed
        kRL(&h0s[q][0][0]);              // DWHH0-L (preloaded)
        LBL(OFF_DWIH0);
        kRH(&h0s[q][0][0]);              // DWHH0-H
        LBH(OFF_DWIH0);
        kRL(&h1s[q ^ 1][0][0]);          // DWIH0-L
        kRH(&h1s[q ^ 1][0][0]);          // DWIH0-H
        LBL(OFF_DWHH1);                  // phase-B preload, under act0
        act(c0s, &h0s[q ^ 1][0][0]);
        __builtin_amdgcn_sched_barrier(0);
        __syncthreads();                 // BAR1: h0d(s) published
        // Phase B: gates3 = b3 + h1d(s-1)*DWhh1 + h0d(s)*DWih1 -> h1d(s)
        LBH(OFF_DWHH1);
        zacc(3);
        kRL(&h1s[q ^ 1][0][0]);          // DWHH1-L (preloaded)
        LBL(OFF_DWIH1);
        kRH(&h1s[q ^ 1][0][0]);          // DWHH1-H
        LBH(OFF_DWIH1);
        kRL(&h0s[q ^ 1][0][0]);          // DWIH1-L
        LBL(OFF_DWHH0);                  // next step's A preload (dead loads at s=19, harmless)
        kRH(&h0s[q ^ 1][0][0]);          // DWIH1-H
        act(c1s, &h1s[q][0][0]);
        __builtin_amdgcn_sched_barrier(0);
        __syncthreads();                 // BAR2: h1d(s) published
    }
    fcOut(OLEN - 1, (OLEN - 1) & 1);     // last step's fc
    #undef LBL
    #undef LBH
}

extern "C" void kernel_launch(void* const* d_in, const int* in_sizes, int n_in,
                              void* d_out, int out_size, void* d_ws, size_t ws_size,
                              hipStream_t stream) {
    const float* x     = (const float*)d_in[0];
    const float* eWih0 = (const float*)d_in[1];
    const float* eWhh0 = (const float*)d_in[2];
    const float* ebi0  = (const float*)d_in[3];
    const float* ebh0  = (const float*)d_in[4];
    const float* eWih1 = (const float*)d_in[5];
    const float* eWhh1 = (const float*)d_in[6];
    const float* ebi1  = (const float*)d_in[7];
    const float* ebh1  = (const float*)d_in[8];
    const float* dWih0 = (const float*)d_in[9];
    const float* dWhh0 = (const float*)d_in[10];
    const float* dbi0  = (const float*)d_in[11];
    const float* dbh0  = (const float*)d_in[12];
    const float* dWih1 = (const float*)d_in[13];
    const float* dWhh1 = (const float*)d_in[14];
    const float* dbi1  = (const float*)d_in[15];
    const float* dbh1  = (const float*)d_in[16];
    const float* fcW   = (const float*)d_in[17];
    const float* fcb   = (const float*)d_in[18];

    f16*   w16 = (f16*)d_ws;
    float* bws = (float*)((char*)d_ws + OFF_BIAS_B);

    prep_kernel<<<256, 256, 0, stream>>>(eWih0, eWhh0, eWih1, eWhh1,
                                         dWih0, dWhh0, dWih1, dWhh1,
                                         ebi0, ebh0, ebi1, ebh1,
                                         dbi0, dbh0, dbi1, dbh1,
                                         fcW, w16, bws);
    lstm_kernel<<<NB / RR, 512, 0, stream>>>(x, w16, bws, fcb, (float*)d_out);
}

// Round 13
// 1543.514 us; speedup vs baseline: 1.4112x; 1.4112x over previous
//
#include <hip/hip_runtime.h>
#include <stdint.h>
#include <stddef.h>

typedef _Float16 f16;
typedef _Float16 f16x8 __attribute__((ext_vector_type(8)));
typedef float    f32x4 __attribute__((ext_vector_type(4)));

#define NB    16384   // batch
#define TT    100     // encoder steps
#define II    6       // input features
#define HH    128     // hidden
#define OLEN  20      // decoder steps
#define OO    2       // output features
#define RR    64      // batch rows per block

// f16-element offsets into workspace (8 recurrent mats are [512][128] = 65536 f16)
#define OFF_WHH0   0
#define OFF_WIH1   65536
#define OFF_WHH1   131072
#define OFF_DWIH0  196608
#define OFF_DWHH0  262144
#define OFF_DWIH1  327680
#define OFF_DWHH1  393216
#define OFF_WIH0P  458752          // [512][8] zero-padded (K=6 -> 8), prescaled
#define OFF_FCW    462848          // [2][128], NOT prescaled
#define OFF_BIAS_B 926208          // byte offset: 4*512 f32 combined prescaled biases
#define WS_BYTES   934400

#define SWZ(r) (((r) & 15) << 3)   // f16-unit XOR swizzle for h tiles

__device__ __forceinline__ float exp2_(float x) {
#if __has_builtin(__builtin_amdgcn_exp2f)
    return __builtin_amdgcn_exp2f(x);
#else
    return exp2f(x);
#endif
}
__device__ __forceinline__ float rcp_(float x) {
#if __has_builtin(__builtin_amdgcn_rcpf)
    return __builtin_amdgcn_rcpf(x);
#else
    return 1.f / x;
#endif
}

// ---------------- weight prep: fp32 -> f16, gate-prescaled; fuse+prescale biases ----
// gate rows (i,f,o) scaled by -log2(e) so sigmoid(z) = rcp(1+exp2(u));
// gate rows (g)     scaled by 2*log2(e) so tanh(z) = 1 - 2*rcp(1+exp2(u)).
__global__ __launch_bounds__(256) void prep_kernel(
    const float* eWih0, const float* eWhh0, const float* eWih1, const float* eWhh1,
    const float* dWih0, const float* dWhh0, const float* dWih1, const float* dWhh1,
    const float* ebi0,  const float* ebh0,  const float* ebi1,  const float* ebh1,
    const float* dbi0,  const float* dbh0,  const float* dbi1,  const float* dbh1,
    const float* fcW,   f16* w16, float* bws)
{
    const float GS0 = -1.4426950408889634f;   // i, f, o
    const float GS2 =  2.8853900817779268f;   // g
    int i0 = blockIdx.x * blockDim.x + threadIdx.x;
    int stride = gridDim.x * blockDim.x;
    const float* srcs[7] = {eWhh0, eWih1, eWhh1, dWih0, dWhh0, dWih1, dWhh1};
    for (int i = i0; i < 7 * 65536; i += stride) {
        int rem = i & 65535;
        float s = ((rem >> 14) == 2) ? GS2 : GS0;
        w16[i] = (f16)(srcs[i >> 16][rem] * s);
    }
    for (int i = i0; i < 512 * 8; i += stride) {
        int n = i >> 3, k = i & 7;
        float s = ((n >> 7) == 2) ? GS2 : GS0;
        w16[OFF_WIH0P + i] = (k < II) ? (f16)(eWih0[n * II + k] * s) : (f16)0.f;
    }
    for (int i = i0; i < OO * HH; i += stride) w16[OFF_FCW + i] = (f16)fcW[i];
    const float* bia[4] = {ebi0, ebi1, dbi0, dbi1};
    const float* bib[4] = {ebh0, ebh1, dbh0, dbh1};
    for (int i = i0; i < 4 * 512; i += stride) {
        int j = i & 511;
        float s = ((j >> 7) == 2) ? GS2 : GS0;
        bws[i] = (bia[i >> 9][j] + bib[i >> 9][j]) * s;
    }
}

// ---------------- main persistent LSTM kernel: 1 block = 64 batch rows ----------------
// SESSION-FINAL: R23 structure (1548us, verified R7/R11/R13).
// Why this is the floor for this structure (R17-R28 evidence):
//  - latency/dependency-bound: MfmaUtil 22 + VALUBusy 37 = ~60% issue at
//    2 waves/SIMD; residual 40% = barrier drain (vmcnt(0)+s_barrier) + L2
//    weight-stream latency. HBM 0.2% (FETCH 23.8MB, WRITE 2.56MB, clean).
//  - HARD register envelope ~128 arch + 64 acc: resident VGPR bank (R21),
//    AGPR-pinned bank (R22), dual accumulators (R24), act+GEMM fusion (R28)
//    all SPILL (WRITE_SIZE 60MB-3GB signatures). act temps and the full
//    weight bank cannot be co-live; R23's disjoint act/GEMM regions are
//    exactly what fits.
//  - 4 waves/SIMD needs arch<=64 (HW granule 64; occupancy 45-47% achieved
//    in R25/R26) but the inner loop needs ~75-85 arch regs -> always spills.
//  - pure reorderings (anti-phase R17) regress on code footprint.
// R23's schedule: half-bank (32-reg) streamed bursts, each 8-load burst
// covered by the other half's MFMAs or an act; next region's WHH0-L
// preloads under act1; decoder fc(s-1) folded into phase A(s).
__global__ __launch_bounds__(512, 2) void lstm_kernel(
    const float* __restrict__ xg, const f16* __restrict__ wsf,
    const float* __restrict__ bws, const float* __restrict__ fcb,
    float* __restrict__ out)
{
    __shared__ __align__(16) f16 h0s[2][RR][HH];     // 32KB, XOR-swizzled
    __shared__ __align__(16) f16 h1s[2][RR][HH];     // 32KB
    __shared__ __align__(16) f16 xs[2][RR][8];       // 2KB
    __shared__ __align__(16) f16 fcws[OO * HH];      // .5KB
    __shared__ float bias_s[4 * 512];                // 8KB
    __shared__ f32x4 c0s[4][512];                    // 32KB cell-0 state (per-thread slots)
    __shared__ f32x4 c1s[4][512];                    // 32KB cell-1 state -> 138.5KB

    const int tid = threadIdx.x;
    const int w   = tid >> 6;      // wave 0..7 -> hidden cols 16w..16w+15
    const int ln  = tid & 63;
    const int l15 = ln & 15;
    const int lg  = ln >> 4;       // lane k-group
    const int r0  = blockIdx.x * RR;

    // ---- init LDS (note: BOTH h1 buffers zeroed -- region 1 reads h1s[1] as h1(-1))
    for (int i = tid; i < OO * HH; i += 512) fcws[i] = wsf[OFF_FCW + i];
    for (int i = tid; i < 4 * 512; i += 512) bias_s[i] = bws[i];
    for (int i = tid; i < RR * HH; i += 512) {
        h0s[0][0][i] = (f16)0.f;
        h1s[0][0][i] = (f16)0.f;
        h1s[1][0][i] = (f16)0.f;
    }
    {
        const f32x4 z4 = {0.f, 0.f, 0.f, 0.f};
        for (int i = tid; i < 4 * 512; i += 512) {
            (&c0s[0][0])[i] = z4;
            (&c1s[0][0])[i] = z4;
        }
    }
    {   // stage x[t=0]
        int r = tid >> 3, k = tid & 7;
        float v = (k < II) ? xg[((size_t)(r0 + r) * TT + 0) * II + k] : 0.f;
        xs[0][r][k] = (f16)v;
    }

    f32x4 acc[4][4];    // [gate][m] accumulators (64 regs, MFMA C/D)
    f16x8 bankL[4][2];  // [gate][kk=0,1] streamed half-bank (32 regs)
    f16x8 bankH[4][2];  // [gate][kk=2,3] streamed half-bank (32 regs)
    f16x8 bX[4];        // encoder x-weights (16 regs; zero in lanes lg>0)

    {
        const f16x8 z = {};
        #pragma unroll
        for (int g = 0; g < 4; ++g) {
            const int nt = (g << 3) + w;
            bX[g] = (lg == 0)
                ? *(const f16x8*)(wsf + OFF_WIH0P + (size_t)((nt << 4) + l15) * 8)
                : z;
        }
    }

    // stream half of one matrix's B-fragments (kk-major). Offset tied through
    // an empty asm so loads re-execute per call (no hoisting into a
    // persistent spill-prone set -- the R5-R11 failure mode).
    auto loadHalfL = [&](unsigned offElems) {
        unsigned off = offElems;
        asm volatile("" : "+v"(off));
        const f16* W = wsf + off;
        #pragma unroll
        for (int kk = 0; kk < 2; ++kk)
            #pragma unroll
            for (int g = 0; g < 4; ++g) {
                const int nt = (g << 3) + w;
                bankL[g][kk] = *(const f16x8*)(W + (size_t)((nt << 4) + l15) * HH + (kk << 5) + (lg << 3));
            }
    };
    auto loadHalfH = [&](unsigned offElems) {
        unsigned off = offElems;
        asm volatile("" : "+v"(off));
        const f16* W = wsf + off;
        #pragma unroll
        for (int kk = 2; kk < 4; ++kk)
            #pragma unroll
            for (int g = 0; g < 4; ++g) {
                const int nt = (g << 3) + w;
                bankH[g][kk - 2] = *(const f16x8*)(W + (size_t)((nt << 4) + l15) * HH + (kk << 5) + (lg << 3));
            }
    };
    // fence + load: sched_barrier stops the new half-burst's loads from
    // hoisting above the previous consumer of that half (liveness doubling).
    #define LBL(off) do { __builtin_amdgcn_sched_barrier(0); loadHalfL(off); } while (0)
    #define LBH(off) do { __builtin_amdgcn_sched_barrier(0); loadHalfH(off); } while (0)

    auto zacc = [&](int cell) {
        #pragma unroll
        for (int g = 0; g < 4; ++g) {
            float b = bias_s[(cell << 9) | (g << 7) | (w << 4) | l15];
            f32x4 b4 = {b, b, b, b};
            #pragma unroll
            for (int m = 0; m < 4; ++m) acc[g][m] = b4;
        }
    };

    // K=64 half-GEMMs over ALL m-tiles with one half-bank (kk-major)
    auto kRL = [&](const f16* hsrc) {
        #pragma unroll
        for (int kk = 0; kk < 2; ++kk)
            #pragma unroll
            for (int m = 0; m < 4; ++m) {
                int r = (m << 4) + l15;
                int c = ((kk << 5) | (lg << 3)) ^ SWZ(r);
                f16x8 a = *(const f16x8*)(hsrc + (size_t)r * HH + c);
                #pragma unroll
                for (int g = 0; g < 4; ++g)
                    acc[g][m] = __builtin_amdgcn_mfma_f32_16x16x32_f16(a, bankL[g][kk], acc[g][m], 0, 0, 0);
            }
    };
    auto kRH = [&](const f16* hsrc) {
        #pragma unroll
        for (int kk = 2; kk < 4; ++kk)
            #pragma unroll
            for (int m = 0; m < 4; ++m) {
                int r = (m << 4) + l15;
                int c = ((kk << 5) | (lg << 3)) ^ SWZ(r);
                f16x8 a = *(const f16x8*)(hsrc + (size_t)r * HH + c);
                #pragma unroll
                for (int g = 0; g < 4; ++g)
                    acc[g][m] = __builtin_amdgcn_mfma_f32_16x16x32_f16(a, bankH[g][kk - 2], acc[g][m], 0, 0, 0);
            }
    };

    // encoder x-term: zero-padded K=32 MFMA (real K=6 in lanes lg==0); no bank dep
    auto mfx = [&](const f16 (*xsrc)[8]) {
        const f16x8 z = {};
        #pragma unroll
        for (int m = 0; m < 4; ++m) {
            int r = (m << 4) + l15;
            f16x8 a = lg ? z : *(const f16x8*)(&xsrc[r][0]);
            #pragma unroll
            for (int g = 0; g < 4; ++g)
                acc[g][m] = __builtin_amdgcn_mfma_f32_16x16x32_f16(a, bX[g], acc[g][m], 0, 0, 0);
        }
    };

    // gate nonlinearities; c in per-thread LDS slots; h -> hdst (parity-[p^1]
    // buffer, never read in the same region -> race-free).
    auto act = [&](f32x4 (*cs)[512], f16* hdst) {
        const int col = (w << 4) + l15;
        #pragma unroll
        for (int m = 0; m < 4; ++m) {
            f32x4 cold = cs[m][tid];
            f32x4 cnew;
            #pragma unroll
            for (int q = 0; q < 4; ++q) {
                float si = rcp_(1.f + exp2_(acc[0][m][q]));
                float sf = rcp_(1.f + exp2_(acc[1][m][q]));
                float tg = 1.f - 2.f * rcp_(1.f + exp2_(acc[2][m][q]));
                float so = rcp_(1.f + exp2_(acc[3][m][q]));
                float cn = sf * cold[q] + si * tg;
                cnew[q] = cn;
                float hn = so * (1.f - 2.f * rcp_(1.f + exp2_(2.8853900817779268f * cn)));
                int r = (m << 4) + (lg << 2) + q;
                hdst[(size_t)r * HH + (col ^ SWZ(r))] = (f16)hn;
            }
            cs[m][tid] = cnew;
        }
    };

    LBL(OFF_WHH0);       // prologue: region 0's phase-A L-half
    __syncthreads();     // init visible

    // ============ encoder: 100 pipelined regions + tail, 1 barrier each ============
    // region t: phaseA(t):  gates0 = b0 + x(t)*Wih0 + h0s[p]*Whh0 -> h0s[p^1], c0
    //           phaseB(t-1):gates1 = b1 + h1s[p]*Whh1 + h0s[p]*Wih1 -> h1s[p^1], c1
    // (h0(t-1) lives in h0s[p]; h1(t-2) in h1s[p] -- all reads pre-region.)
    // Half-bursts are issued as soon as their half is dead, covered by the
    // other half's MFMAs / act; WHH0-L for region t+1 preloads under act1.
    for (int t = 0; t < TT; ++t) {
        const int p = t & 1;
        float xv = 0.f;
        if (t + 1 < TT && (tid & 7) < II)
            xv = xg[((size_t)(r0 + (tid >> 3)) * TT + (t + 1)) * II + (tid & 7)];
        // phase A (WHH0-L preloaded at end of previous region)
        LBH(OFF_WHH0);                   // H-burst streams under zacc+mfx+kRL
        zacc(0);
        mfx(xs[p]);
        kRL(&h0s[p][0][0]);              // WHH0-L
        LBL(OFF_WHH1);                   // covered by kRH + act0
        kRH(&h0s[p][0][0]);              // WHH0-H
        LBH(OFF_WHH1);                   // covered by act0 + kRL(h1)
        act(c0s, &h0s[p ^ 1][0][0]);
        // phase B of step t-1
        if (t > 0) {
            zacc(1);
            kRL(&h1s[p][0][0]);          // WHH1-L (state term h1(t-2))
            LBL(OFF_WIH1);               // covered by kRH(h1)
            kRH(&h1s[p][0][0]);          // WHH1-H
            LBH(OFF_WIH1);               // covered by kRL(h0)
            kRL(&h0s[p][0][0]);          // WIH1-L (input term h0(t-1), OLD buffer)
            LBL(OFF_WHH0);               // next region's A preload, under kRH+act1
            kRH(&h0s[p][0][0]);          // WIH1-H
            act(c1s, &h1s[p ^ 1][0][0]); // h1(t-1)
        } else {
            LBL(OFF_WHH0);               // region 1's A preload
        }
        if (t + 1 < TT) xs[p ^ 1][tid >> 3][tid & 7] = (f16)xv;
        __builtin_amdgcn_sched_barrier(0);
        __syncthreads();                 // ONE barrier per region
    }
    // tail region: phaseB(99). After loop: h0(99)=h0s[0], h1(98)=h1s[0].
    {
        LBL(OFF_WHH1);
        LBH(OFF_WHH1);
        zacc(1);
        kRL(&h1s[0][0][0]);              // h1(98)
        LBL(OFF_WIH1);
        kRH(&h1s[0][0][0]);
        LBH(OFF_WIH1);
        kRL(&h0s[0][0][0]);              // h0(99)
        LBL(OFF_DWHH0);                  // decoder phase-A preload, under kRH+act1
        kRH(&h0s[0][0][0]);
        act(c1s, &h1s[1][0][0]);         // h1(99) -> h1s[1]
        __builtin_amdgcn_sched_barrier(0);
        __syncthreads();
    }
    // decoder entry: h0 cur = h0s[0], h1 cur = h1s[1]

    float fb = (tid < RR * OO) ? fcb[tid & 1] : 0.f;

    // fc: pred[r][o] = h1d(s) . fc_W[o] + fc_b[o]  (threads 0..127 only)
    auto fcOut = [&](int s, int qq) {
        if (tid < RR * OO) {
            int r = tid >> 1, o = tid & 1;
            float a = fb;
            const f16* hrow = &h1s[qq][r][0];
            #pragma unroll
            for (int ccol = 0; ccol < HH; ccol += 8) {
                int csw = ccol ^ SWZ(r);
                f16x8 hv = *(const f16x8*)(hrow + csw);
                f16x8 wv = *(const f16x8*)(&fcws[o * HH + ccol]);
                #pragma unroll
                for (int j = 0; j < 8; ++j) a += (float)hv[j] * (float)wv[j];
            }
            out[((size_t)(r0 + r) * OLEN + s) * OO + o] = a;
        }
    };

    // ============ decoder: 20 steps, 2 barriers/step ============
    // step s (q=s&1): reads h0s[q], h1s[q^1]; writes h0s[q^1] (A), h1s[q] (B).
    // Strictly serial (B(s) needs A(s)'s h0 through the barrier). fc(s-1) is
    // folded into A(s): it reads h1s[q^1], which A(s) only reads; h1s[q^1] is
    // next written at B(s+1), two barriers later -> race-free.
    for (int s = 0; s < OLEN; ++s) {
        const int q = s & 1;
        // Phase A: gates2 = b2 + h0d(s-1)*DWhh0 + h1d(s-1)*DWih0 -> h0d(s)
        LBH(OFF_DWHH0);                  // streams under zacc+fc+kRL
        zacc(2);
        if (s > 0) fcOut(s - 1, q ^ 1);  // waves 0-1 do fc; waves 2-7 proceed
        kRL(&h0s[q][0][0]);              // DWHH0-L (preloaded)
        LBL(OFF_DWIH0);
        kRH(&h0s[q][0][0]);              // DWHH0-H
        LBH(OFF_DWIH0);
        kRL(&h1s[q ^ 1][0][0]);          // DWIH0-L
        kRH(&h1s[q ^ 1][0][0]);          // DWIH0-H
        LBL(OFF_DWHH1);                  // phase-B preload, under act0
        act(c0s, &h0s[q ^ 1][0][0]);
        __builtin_amdgcn_sched_barrier(0);
        __syncthreads();                 // BAR1: h0d(s) published
        // Phase B: gates3 = b3 + h1d(s-1)*DWhh1 + h0d(s)*DWih1 -> h1d(s)
        LBH(OFF_DWHH1);
        zacc(3);
        kRL(&h1s[q ^ 1][0][0]);          // DWHH1-L (preloaded)
        LBL(OFF_DWIH1);
        kRH(&h1s[q ^ 1][0][0]);          // DWHH1-H
        LBH(OFF_DWIH1);
        kRL(&h0s[q ^ 1][0][0]);          // DWIH1-L
        LBL(OFF_DWHH0);                  // next step's A preload (dead loads at s=19, harmless)
        kRH(&h0s[q ^ 1][0][0]);          // DWIH1-H
        act(c1s, &h1s[q][0][0]);
        __builtin_amdgcn_sched_barrier(0);
        __syncthreads();                 // BAR2: h1d(s) published
    }
    fcOut(OLEN - 1, (OLEN - 1) & 1);     // last step's fc
    #undef LBL
    #undef LBH
}

extern "C" void kernel_launch(void* const* d_in, const int* in_sizes, int n_in,
                              void* d_out, int out_size, void* d_ws, size_t ws_size,
                              hipStream_t stream) {
    const float* x     = (const float*)d_in[0];
    const float* eWih0 = (const float*)d_in[1];
    const float* eWhh0 = (const float*)d_in[2];
    const float* ebi0  = (const float*)d_in[3];
    const float* ebh0  = (const float*)d_in[4];
    const float* eWih1 = (const float*)d_in[5];
    const float* eWhh1 = (const float*)d_in[6];
    const float* ebi1  = (const float*)d_in[7];
    const float* ebh1  = (const float*)d_in[8];
    const float* dWih0 = (const float*)d_in[9];
    const float* dWhh0 = (const float*)d_in[10];
    const float* dbi0  = (const float*)d_in[11];
    const float* dbh0  = (const float*)d_in[12];
    const float* dWih1 = (const float*)d_in[13];
    const float* dWhh1 = (const float*)d_in[14];
    const float* dbi1  = (const float*)d_in[15];
    const float* dbh1  = (const float*)d_in[16];
    const float* fcW   = (const float*)d_in[17];
    const float* fcb   = (const float*)d_in[18];

    f16*   w16 = (f16*)d_ws;
    float* bws = (float*)((char*)d_ws + OFF_BIAS_B);

    prep_kernel<<<256, 256, 0, stream>>>(eWih0, eWhh0, eWih1, eWhh1,
                                         dWih0, dWhh0, dWih1, dWhh1,
                                         ebi0, ebh0, ebi1, ebh1,
                                         dbi0, dbh0, dbi1, dbh1,
                                         fcW, w16, bws);
    lstm_kernel<<<NB / RR, 512, 0, stream>>>(x, w16, bws, fcb, (float*)d_out);
}